// Round 12
// baseline (328.051 us; speedup 1.0000x reference)
//
#include <hip/hip_runtime.h>
#include <hip/hip_bf16.h>

#define BT   4096   // B*T
#define CD   1024   // C
#define TD   2048   // T
#define NH   16     // heads
#define DH   64     // head dim
#define BB   2      // batch

typedef __attribute__((ext_vector_type(8))) short bf16x8;
typedef __attribute__((ext_vector_type(4))) short bf16x4;
typedef __attribute__((ext_vector_type(4))) float f32x4;
typedef __attribute__((ext_vector_type(2))) unsigned int u32x2;
typedef __attribute__((ext_vector_type(4))) unsigned int u32x4;

__device__ inline short f2bf(float f) {
    union { float fv; unsigned u; } x; x.fv = f;
    unsigned r = x.u + 0x7fffu + ((x.u >> 16) & 1u);
    return (short)(r >> 16);
}
__device__ inline float bf2f(short s) {
    union { unsigned u; float f; } x; x.u = ((unsigned)(unsigned short)s) << 16;
    return x.f;
}
__device__ inline unsigned pk2bf(float a, float b) {
    union { __hip_bfloat162 h; unsigned u; } cv;
    cv.h = __float22bfloat162_rn(float2{a, b});
    return cv.u;
}

// raw v_exp_f32 (2^x): avoid any OCML guard sequence
#if __has_builtin(__builtin_amdgcn_exp2f)
#define EXP2(x) __builtin_amdgcn_exp2f(x)
#else
#define EXP2(x) exp2f(x)
#endif

__device__ inline void gload_lds16(const short* g, short* lds) {
    __builtin_amdgcn_global_load_lds(
        (const __attribute__((address_space(1))) void*)g,
        (__attribute__((address_space(3))) void*)lds, 16, 0, 0);
}

// ---------------- LayerNorm: one block per row (C=1024), fp32 in, bf16 out ----
// float4 loads (one per thread), row kept in regs, short4 output store.
__launch_bounds__(256)
__global__ void ln_kernel(const float* __restrict__ x,
                          const float* __restrict__ g,
                          const float* __restrict__ be,
                          short* __restrict__ out) {
    __shared__ float red[2][4];
    const int row = blockIdx.x;
    const int c4 = threadIdx.x * 4;
    const float* xr = x + (size_t)row * CD;
    float4 v = *(const float4*)&xr[c4];
    float s  = (v.x + v.y) + (v.z + v.w);
    float ss = (v.x * v.x + v.y * v.y) + (v.z * v.z + v.w * v.w);
    #pragma unroll
    for (int off = 32; off > 0; off >>= 1) {
        s  += __shfl_down(s,  off, 64);
        ss += __shfl_down(ss, off, 64);
    }
    int wid = threadIdx.x >> 6, lane = threadIdx.x & 63;
    if (lane == 0) { red[0][wid] = s; red[1][wid] = ss; }
    __syncthreads();
    float sum   = red[0][0] + red[0][1] + red[0][2] + red[0][3];
    float sumsq = red[1][0] + red[1][1] + red[1][2] + red[1][3];
    float mu   = sum * (1.f / CD);
    float var  = sumsq * (1.f / CD) - mu * mu;
    float rstd = rsqrtf(var + 1e-5f);
    float4 gv = *(const float4*)&g[c4];
    float4 bv = *(const float4*)&be[c4];
    bf16x4 o;
    o[0] = f2bf((v.x - mu) * rstd * gv.x + bv.x);
    o[1] = f2bf((v.y - mu) * rstd * gv.y + bv.y);
    o[2] = f2bf((v.z - mu) * rstd * gv.z + bv.z);
    o[3] = f2bf((v.w - mu) * rstd * gv.w + bv.w);
    *(bf16x4*)&out[(size_t)row * CD + c4] = o;
}

// ------------- Fused weight prep: all 64x64 fp32->bf16 transpose tiles -------
// blocks 0..767: Wq/Wk/Wv (per-head CDxDH slices) -> wqt (3,H,DH,C)
// 768..1023: Wo (CDxCD); 1024..2047: W1 (CDx4CD); 2048..3071: W2 (4CDxCD)
__launch_bounds__(256)
__global__ void prep_weights(const float* __restrict__ Wq, const float* __restrict__ Wk,
                             const float* __restrict__ Wv, const float* __restrict__ Wo,
                             const float* __restrict__ W1, const float* __restrict__ W2,
                             short* __restrict__ wqt, short* __restrict__ wot,
                             short* __restrict__ w1t, short* __restrict__ w2t) {
    __shared__ float tt[64][65];
    const int id = blockIdx.x;
    const float* in; short* out; int R, Cc, r0, c0;
    if (id < 768) {
        int which = id >> 8, rem = id & 255, hh = rem >> 4, ry = rem & 15;
        in  = (which == 0 ? Wq : which == 1 ? Wk : Wv) + (size_t)hh * CD * DH;
        out = wqt + (size_t)which * CD * CD + (size_t)hh * DH * CD;
        R = CD; Cc = DH; r0 = ry * 64; c0 = 0;
    } else if (id < 1024) {
        int t = id - 768;  in = Wo; out = wot; R = CD;     Cc = CD;     r0 = (t >> 4) * 64; c0 = (t & 15) * 64;
    } else if (id < 2048) {
        int t = id - 1024; in = W1; out = w1t; R = CD;     Cc = 4 * CD; r0 = (t >> 6) * 64; c0 = (t & 63) * 64;
    } else {
        int t = id - 2048; in = W2; out = w2t; R = 4 * CD; Cc = CD;     r0 = (t >> 4) * 64; c0 = (t & 15) * 64;
    }
    const int tid = threadIdx.x;
    #pragma unroll
    for (int i = 0; i < 4; ++i) {
        int f = i * 256 + tid;             // float4 index within 64x64 tile
        int r = f >> 4, cc = (f & 15) * 4;
        float4 vv = *(const float4*)&in[(size_t)(r0 + r) * Cc + c0 + cc];
        tt[r][cc]     = vv.x;
        tt[r][cc + 1] = vv.y;
        tt[r][cc + 2] = vv.z;
        tt[r][cc + 3] = vv.w;
    }
    __syncthreads();
    #pragma unroll
    for (int i = 0; i < 16; ++i) {
        int e = i * 256 + tid;
        out[(size_t)(c0 + (e >> 6)) * R + r0 + (e & 63)] = f2bf(tt[e & 63][e >> 6]);
    }
}

// ------------- V transpose: vbf (BT x C bf16) -> vtg[b][h][d][t] bf16 -------
__launch_bounds__(256)
__global__ void vtrans(const short* __restrict__ vin, short* __restrict__ vout) {
    __shared__ short t[64 * 65];
    const int tid = threadIdx.x;
    const int bh = blockIdx.y;
    const int t0 = blockIdx.x * 64;
    const int b = bh >> 4, h = bh & 15;
    const short* src = vin + (size_t)b * TD * CD + (size_t)h * DH;
    short* dst = vout + (size_t)bh * DH * TD;
    #pragma unroll
    for (int i = 0; i < 16; ++i) {
        int e = i * 256 + tid;
        t[(e >> 6) * 65 + (e & 63)] = src[(size_t)(t0 + (e >> 6)) * CD + (e & 63)];
    }
    __syncthreads();
    #pragma unroll
    for (int i = 0; i < 16; ++i) {
        int e = i * 256 + tid;
        int d = e >> 6, tt = e & 63;
        dst[(size_t)d * TD + t0 + tt] = t[tt * 65 + d];
    }
}

// ---------------- MFMA GEMM: C(128 x TN) = A(M x K) . Bt(N x K)^T, bf16 ------
// GR=1: triple-buffered, depth-2 prefetch (vmcnt 4/6).
// GR=2 (512 thr): in-block split-K, 4 buffers/group, depth-3, vmcnt(8).
// GR=4 (1024 thr, R20): 4 K-groups x NBUF=2 double-buffer (128KB LDS),
//   16 waves/CU at the grid-forced 1 block/CU; counted vmcnt(4) 2-barrier
//   loop (peeled vmcnt(0) tail); 4-round mt-sliced LDS reduction tree
//   (g1-3 write 48KB -> g0 adds), all threads hit every barrier.
// XOR-swizzled 16B slots -> conflict-free ds_read_b128, linear gload dest.
// XCD-aware tile swizzle: XCD k = li&7 owns m-tiles [4k,4k+4) x all n-tiles.
// MODE 1: + bias + fp32 resid -> fp32 out
// MODE 2: + bias, relu -> bf16 out
// MODE 5: QKV merged: N=3072; seg=col>>10 -> outb + seg*BT*CD; seg0 scaled
template <int MODE, int TN, int GR>
__launch_bounds__(GR * 256)
__global__ void gemm_mfma(const short* __restrict__ A,
                          const short* __restrict__ Bt,
                          const float* __restrict__ bias,
                          const float* __restrict__ resid,
                          float* __restrict__ outf,
                          short* __restrict__ outb,
                          int N, int K) {
    constexpr int NBUF = (GR == 2) ? 4 : ((GR == 4) ? 2 : 3);
    __shared__ __align__(16) short smem[GR * NBUF * (128 + TN) * 32];
    const int tid = threadIdx.x;
    const int kgrp = (GR > 1) ? (tid >> 8) : 0;
    const int tid256 = tid & 255;
    const int w4 = tid256 >> 6, lane = tid & 63;
    const int quad = lane >> 4, l16 = lane & 15;
    const int wr = w4 >> 1, wc = w4 & 1;
    // XCD-aware swizzle: li -> (m-tile, n-tile); XCD k = li&7 owns m 4k..4k+4
    const int li = blockIdx.y * gridDim.x + blockIdx.x;
    const int m0 = ((li & 7) * 4 + ((li >> 3) & 3)) * 128;
    const int n0 = (li >> 5) * TN;
    const int NT = TN / 32;
    const int kbase = kgrp * (K / GR);

    short* grpBase = smem + (size_t)kgrp * NBUF * (128 + TN) * 32;
#define AS(bi) (grpBase + (bi) * (128 + TN) * 32)
#define BS(bi) (AS(bi) + 128 * 32)

    f32x4 acc[4][NT] = {};

    auto STAGE = [&](int kt, int bi) {
        const int k0 = kbase + kt * 32;
        short* as = AS(bi);
        short* bs = BS(bi);
        #pragma unroll
        for (int i = 0; i < 2; ++i) {
            int s = i * 256 + tid256;
            int row = s >> 2, kc = (s & 3) ^ ((row >> 1) & 3);
            gload_lds16(A + (size_t)(m0 + row) * K + k0 + kc * 8,
                        &as[(i * 256 + w4 * 64) * 8]);
        }
        #pragma unroll
        for (int i = 0; i < TN / 64; ++i) {
            int s = i * 256 + tid256;
            int row = s >> 2, kc = (s & 3) ^ ((row >> 1) & 3);
            gload_lds16(Bt + (size_t)(n0 + row) * K + k0 + kc * 8,
                        &bs[(i * 256 + w4 * 64) * 8]);
        }
    };

    auto COMPUTE = [&](int bi) {
        const int xo = (quad ^ ((l16 >> 1) & 3)) * 8;
        const short* as = AS(bi);
        const short* bs = BS(bi);
        bf16x8 a[4], b[NT];
        #pragma unroll
        for (int mt = 0; mt < 4; ++mt)
            a[mt] = *(const bf16x8*)&as[(wr * 64 + mt * 16 + l16) * 32 + xo];
        #pragma unroll
        for (int nt = 0; nt < NT; ++nt)
            b[nt] = *(const bf16x8*)&bs[(wc * (TN / 2) + nt * 16 + l16) * 32 + xo];
        #pragma unroll
        for (int mt = 0; mt < 4; ++mt)
            #pragma unroll
            for (int nt = 0; nt < NT; ++nt)
                acc[mt][nt] = __builtin_amdgcn_mfma_f32_16x16x32_bf16(a[mt], b[nt], acc[mt][nt], 0, 0, 0);
    };

    const int nk = (K / GR) >> 5;
    if (GR == 4) {
        // NBUF=2 double-buffer, counted vmcnt(4), 2 barriers/step
        STAGE(0, 0);
        STAGE(1, 1);
        for (int t = 0; t < nk - 1; ++t) {
            asm volatile("s_waitcnt vmcnt(4)" ::: "memory");
            __builtin_amdgcn_s_barrier();
            asm volatile("" ::: "memory");
            COMPUTE(t & 1);
            __builtin_amdgcn_s_barrier();
            asm volatile("" ::: "memory");
            if (t + 2 < nk) STAGE(t + 2, t & 1);
        }
        asm volatile("s_waitcnt vmcnt(0)" ::: "memory");
        __builtin_amdgcn_s_barrier();
        asm volatile("" ::: "memory");
        COMPUTE((nk - 1) & 1);
    } else if (GR == 2) {
        // depth-3: tiles t, t+1, t+2 in flight (4 loads each per thread)
        STAGE(0, 0);
        STAGE(1, 1);
        STAGE(2, 2);
        for (int t = 0; t < nk - 2; ++t) {
            asm volatile("s_waitcnt vmcnt(8)" ::: "memory");
            __builtin_amdgcn_s_barrier();
            asm volatile("" ::: "memory");
            if (t + 3 < nk) STAGE(t + 3, (t + 3) & 3);
            COMPUTE(t & 3);
        }
        asm volatile("s_waitcnt vmcnt(4)" ::: "memory");
        __builtin_amdgcn_s_barrier();
        asm volatile("" ::: "memory");
        COMPUTE((nk - 2) & 3);
        asm volatile("s_waitcnt vmcnt(0)" ::: "memory");
        __builtin_amdgcn_s_barrier();
        asm volatile("" ::: "memory");
        COMPUTE((nk - 1) & 3);
    } else {
        // depth-2, 3 buffers
        STAGE(0, 0);
        STAGE(1, 1);
        int bi = 0;
        for (int t = 0; t < nk - 1; ++t) {
            if (TN == 256) asm volatile("s_waitcnt vmcnt(6)" ::: "memory");
            else           asm volatile("s_waitcnt vmcnt(4)" ::: "memory");
            __builtin_amdgcn_s_barrier();
            asm volatile("" ::: "memory");
            int bn = bi + 2 >= 3 ? bi - 1 : bi + 2;
            if (t + 2 < nk) STAGE(t + 2, bn);
            COMPUTE(bi);
            bi = bi + 1 >= 3 ? 0 : bi + 1;
        }
        asm volatile("s_waitcnt vmcnt(0)" ::: "memory");
        __builtin_amdgcn_s_barrier();
        asm volatile("" ::: "memory");
        COMPUTE(bi);
    }

    if (GR == 4) {
        // 4-round mt-sliced reduction tree: g1-3 -> LDS (16KB regions), g0 adds
        float* red = (float*)smem;
        #pragma unroll
        for (int mt = 0; mt < 4; ++mt) {
            __syncthreads();
            if (kgrp != 0) {
                #pragma unroll
                for (int nt = 0; nt < NT; ++nt)
                    *(f32x4*)&red[(size_t)(kgrp - 1) * 4096 + (nt * 256 + w4 * 64 + lane) * 4] = acc[mt][nt];
            }
            __syncthreads();
            if (kgrp == 0) {
                #pragma unroll
                for (int nt = 0; nt < NT; ++nt) {
                    int off = (nt * 256 + w4 * 64 + lane) * 4;
                    f32x4 p1 = *(const f32x4*)&red[off];
                    f32x4 p2 = *(const f32x4*)&red[4096 + off];
                    f32x4 p3 = *(const f32x4*)&red[8192 + off];
                    acc[mt][nt] += (p1 + p2) + p3;
                }
            }
        }
        if (kgrp != 0) return;
    } else if (GR == 2) {
        // cross-group reduction: group1 acc -> LDS (slice-major, conflict-free)
        float* red = (float*)smem;
        __syncthreads();   // staging LDS dead; safe to alias
        if (kgrp == 1) {
            #pragma unroll
            for (int mt = 0; mt < 4; ++mt)
                #pragma unroll
                for (int nt = 0; nt < NT; ++nt)
                    *(f32x4*)&red[((mt * NT + nt) * 256 + w4 * 64 + lane) * 4] = acc[mt][nt];
        }
        __syncthreads();
        if (kgrp == 1) return;
        #pragma unroll
        for (int mt = 0; mt < 4; ++mt)
            #pragma unroll
            for (int nt = 0; nt < NT; ++nt) {
                f32x4 p = *(const f32x4*)&red[((mt * NT + nt) * 256 + w4 * 64 + lane) * 4];
                acc[mt][nt] += p;
            }
    }

    const float qsc = (MODE == 5 && n0 < CD) ? 0.03125f * 1.44269504f : 1.0f;
    short* ob5 = (MODE == 5) ? outb + (size_t)(n0 >> 10) * BT * CD : nullptr;

    #pragma unroll
    for (int mt = 0; mt < 4; ++mt)
        #pragma unroll
        for (int nt = 0; nt < NT; ++nt)
            #pragma unroll
            for (int reg = 0; reg < 4; ++reg) {
                int row = m0 + wr * 64 + mt * 16 + quad * 4 + reg;
                int col = n0 + wc * (TN / 2) + nt * 16 + l16;
                float v = acc[mt][nt][reg];
                if (MODE == 1) { v += bias[col] + resid[(size_t)row * N + col];
                                 outf[(size_t)row * N + col] = v; }
                if (MODE == 2) { v = fmaxf(v + bias[col], 0.f);
                                 outb[(size_t)row * N + col] = f2bf(v); }
                if (MODE == 5) { ob5[(size_t)row * CD + (col & 1023)] = f2bf(v * qsc); }
            }
#undef AS
#undef BS
}

// ---------------- Flash attention, split-K, MFMA bf16, no-max softmax --------
// R9 version (best measured attn: 49.2us, FETCH 69.7MB): staging via
// global_load_lds (T21 source permutation; LDS dest linear), BK=32 unpadded
// 8KB buffers, TRIPLE-buffered, counted vmcnt(2) never-drain, 5 blocks/CU.
// Swizzles (2-way max = free):
//   K [32][64]: store chunk c' = c ^ (row&7);  read chunk x ^ (l16&7)
//   V [64][32]: store chunk c' = c ^ ((row>>1)&3); read chunk quad^((l16>>1)&3)
// K=32 PV via permuted-K storage (R14) and l-sum via MFMA ones (R15).
#define BQ   128
#define BK   32

__launch_bounds__(256, 5)
__global__ void attn_mfma(const short* __restrict__ q,
                          const short* __restrict__ k,
                          const short* __restrict__ vt,
                          short* __restrict__ opart,
                          float* __restrict__ lpart) {
    __shared__ short Ks[3][BK * DH];   // [32][64]
    __shared__ short Vt[3][DH * BK];   // [64][32]

    const int tid  = threadIdx.x;
    const int w = tid >> 6, lane = tid & 63;
    const int quad = lane >> 4, l16 = lane & 15;
    const int h = blockIdx.y;
    const int b = blockIdx.z >> 1, split = blockIdx.z & 1;
    const int q0 = blockIdx.x * BQ;
    const size_t base  = (size_t)b * TD * CD + (size_t)h * DH;
    const size_t vbase = (size_t)(b * NH + h) * DH * TD;

    // Q frags (N-side of S^T mfma): lane holds Q[q=l16][d=quad*8+j]
    bf16x8 qf[2][2];
    #pragma unroll
    for (int rt = 0; rt < 2; ++rt) {
        const short* qp = q + base + (size_t)(q0 + w * 32 + rt * 16 + l16) * CD;
        qf[rt][0] = *(const bf16x8*)&qp[quad * 8];
        qf[rt][1] = *(const bf16x8*)&qp[32 + quad * 8];
    }

    const bf16x8 ones = {(short)0x3F80, (short)0x3F80, (short)0x3F80, (short)0x3F80,
                         (short)0x3F80, (short)0x3F80, (short)0x3F80, (short)0x3F80};
    f32x4 O_l[2] = {};   // l accumulator: row q=quad*4+reg (col replicated)
    f32x4 O[2][4] = {};

    const int kbeg = split * (TD / 2);
    const int NTI = (TD / 2) / BK;   // 32

    // --- per-lane staging source coords (computed once) ---
    const int ks  = tid >> 3;
    const int kc  = (tid & 7) ^ (ks & 7);
    const int kkey = (((ks & 15) >> 2) << 3) + (ks & 3) + ((ks >> 4) << 2);
    const short* kgp = k + base + (size_t)kkey * CD + kc * 8;   // + (kbeg+kt*BK)*CD
    const int vd = tid >> 2;
    const int vc = (tid & 3) ^ ((vd >> 1) & 3);
    const short* vgp = vt + vbase + (size_t)vd * TD + vc * 8;   // + kbeg+kt*BK

#define STAGE_T(kt, bi) do {                                              \
        const size_t ko_ = (size_t)(kbeg + (kt) * BK);                    \
        gload_lds16(kgp + ko_ * CD, &Ks[bi][w * 512]);                    \
        gload_lds16(vgp + ko_,      &Vt[bi][w * 512]);                    \
    } while (0)

#define COMPUTE_T(bi) do {                                                \
        __builtin_amdgcn_s_setprio(1);                                    \
        const int kswz = l16 & 7;                                         \
        bf16x8 kbe0 = *(const bf16x8*)&Ks[bi][l16 * 64 + ((quad) ^ kswz) * 8];        \
        bf16x8 kbe1 = *(const bf16x8*)&Ks[bi][l16 * 64 + ((4 + quad) ^ kswz) * 8];    \
        bf16x8 kbo0 = *(const bf16x8*)&Ks[bi][(16 + l16) * 64 + ((quad) ^ kswz) * 8]; \
        bf16x8 kbo1 = *(const bf16x8*)&Ks[bi][(16 + l16) * 64 + ((4 + quad) ^ kswz) * 8]; \
        bf16x8 pa8[2];                                                    \
        _Pragma("unroll")                                                 \
        for (int rt = 0; rt < 2; ++rt) {                                  \
            f32x4 ae = (f32x4){0.f, 0.f, 0.f, 0.f};                       \
            f32x4 ao = (f32x4){0.f, 0.f, 0.f, 0.f};                       \
            ae = __builtin_amdgcn_mfma_f32_16x16x32_bf16(kbe0, qf[rt][0], ae, 0, 0, 0); \
            ae = __builtin_amdgcn_mfma_f32_16x16x32_bf16(kbe1, qf[rt][1], ae, 0, 0, 0); \
            ao = __builtin_amdgcn_mfma_f32_16x16x32_bf16(kbo0, qf[rt][0], ao, 0, 0, 0); \
            ao = __builtin_amdgcn_mfma_f32_16x16x32_bf16(kbo1, qf[rt][1], ao, 0, 0, 0); \
            float pe0 = EXP2(ae[0]), pe1 = EXP2(ae[1]);                   \
            float pe2 = EXP2(ae[2]), pe3 = EXP2(ae[3]);                   \
            float po0 = EXP2(ao[0]), po1 = EXP2(ao[1]);                   \
            float po2 = EXP2(ao[2]), po3 = EXP2(ao[3]);                   \
            union { u32x4 u; bf16x8 s; } cv_;                             \
            cv_.u = (u32x4){pk2bf(pe0, pe1), pk2bf(pe2, pe3),             \
                            pk2bf(po0, po1), pk2bf(po2, po3)};            \
            pa8[rt] = cv_.s;                                              \
        }                                                                 \
        const int vswz = (l16 >> 1) & 3;                                  \
        _Pragma("unroll")                                                 \
        for (int dt = 0; dt < 4; ++dt) {                                  \
            bf16x8 vb = *(const bf16x8*)&Vt[bi][(dt * 16 + l16) * 32 + ((quad) ^ vswz) * 8]; \
            O[0][dt] = __builtin_amdgcn_mfma_f32_16x16x32_bf16(pa8[0], vb, O[0][dt], 0, 0, 0); \
            O[1][dt] = __builtin_amdgcn_mfma_f32_16x16x32_bf16(pa8[1], vb, O[1][dt], 0, 0, 0); \
        }                                                                 \
        O_l[0] = __builtin_amdgcn_mfma_f32_16x16x32_bf16(pa8[0], ones, O_l[0], 0, 0, 0); \
        O_l[1] = __builtin_amdgcn_mfma_f32_16x16x32_bf16(pa8[1], ones, O_l[1], 0, 0, 0); \
        __builtin_amdgcn_s_setprio(0);                                    \
    } while (0)

    // prologue: tiles 0,1 in flight (2 gload_lds each per thread)
    STAGE_T(0, 0);
    STAGE_T(1, 1);
    int bi = 0;
    for (int t = 0; t < NTI - 1; ++t) {
        // counted wait: tile t's 2 loads done; tile t+1's 2 (youngest) fly
        asm volatile("s_waitcnt vmcnt(2)" ::: "memory");
        __builtin_amdgcn_s_barrier();
        asm volatile("" ::: "memory");
        int bn = bi + 2 >= 3 ? bi - 1 : bi + 2;
        if (t + 2 < NTI) STAGE_T(t + 2, bn);
        COMPUTE_T(bi);
        bi = bi + 1 >= 3 ? 0 : bi + 1;
    }
    asm volatile("s_waitcnt vmcnt(0)" ::: "memory");
    __builtin_amdgcn_s_barrier();
    asm volatile("" ::: "memory");
    COMPUTE_T(bi);
#undef STAGE_T
#undef COMPUTE_T

    // epilogue: unnormalized O (bf16) + l (fp32) per split
    short* osp = opart + (size_t)split * BT * CD;
    float* lsp = lpart + (size_t)split * BB * NH * TD + (size_t)(b * NH + h) * TD;
    #pragma unroll
    for (int rt = 0; rt < 2; ++rt) {
        if (l16 == 0)
            *(f32x4*)&lsp[q0 + w * 32 + rt * 16 + quad * 4] = O_l[rt];
        #pragma unroll
        for (int reg = 0; reg < 4; ++reg) {
            int row = q0 + w * 32 + rt * 16 + quad * 4 + reg;
            short* op = osp + base + (size_t)row * CD;
            #pragma unroll
            for (int dt = 0; dt < 4; ++dt)
                op[dt * 16 + l16] = f2bf(O[rt][dt][reg]);
        }
    }
}

// ---------------- Combine split-K partials: ob = (O0+O1)/(l0+l1), bf16 -------
__launch_bounds__(256)
__global__ void attn_combine(const short* __restrict__ opart,
                             const float* __restrict__ lpart,
                             short* __restrict__ ob) {
    const size_t idx = ((size_t)blockIdx.x * 256 + threadIdx.x) * 8;
    const int row = (int)(idx >> 10);        // / CD
    const int col = (int)(idx & 1023);
    const int b = row >> 11, qq = row & (TD - 1), hh = col >> 6;
    const size_t lbase = (size_t)(b * NH + hh) * TD + qq;
    const float l0 = lpart[lbase];
    const float l1 = lpart[(size_t)BB * NH * TD + lbase];
    const float inv = 1.f / (l0 + l1);
    bf16x8 a = *(const bf16x8*)&opart[idx];
    bf16x8 c = *(const bf16x8*)&opart[(size_t)BT * CD + idx];
    bf16x8 r;
    #pragma unroll
    for (int j = 0; j < 8; ++j)
        r[j] = f2bf((bf2f(a[j]) + bf2f(c[j])) * inv);
    *(bf16x8*)&ob[idx] = r;
}

extern "C" void kernel_launch(void* const* d_in, const int* in_sizes, int n_in,
                              void* d_out, int out_size, void* d_ws, size_t ws_size,
                              hipStream_t stream) {
    const float* x   = (const float*)d_in[0];
    const float* Wq  = (const float*)d_in[1];
    const float* Wk  = (const float*)d_in[2];
    const float* Wv  = (const float*)d_in[3];
    const float* Wo  = (const float*)d_in[4];
    const float* bo  = (const float*)d_in[5];
    const float* W1  = (const float*)d_in[6];
    const float* b1  = (const float*)d_in[7];
    const float* W2  = (const float*)d_in[8];
    const float* b2  = (const float*)d_in[9];
    const float* g1  = (const float*)d_in[10];
    const float* be1 = (const float*)d_in[11];
    const float* g2  = (const float*)d_in[12];
    const float* be2 = (const float*)d_in[13];
    float* out = (float*)d_out;

    const size_t SZ = (size_t)BT * CD;  // 4M elements
    float* ws  = (float*)d_ws;
    short* qbf = (short*)ws;                       // [0,1.5SZ): q|k|v bf16
    short* kbf = qbf + SZ;
    short* vbf = qbf + 2 * SZ;
    float* lpart = ws + SZ + SZ / 2;               // [1.5SZ,+128K floats)
    short* opart = (short*)(ws + 2 * SZ);          // [2SZ,3SZ): 2 x SZ bf16
    float* x1  = ws + 2 * SZ;                      // [2SZ,3SZ): after combine
    short* h   = (short*)(ws + 3 * SZ);            // [3SZ,3.5SZ)
    short* ob  = (short*)(ws + 3 * SZ + SZ / 2);   // [3.5SZ,4SZ)
    short* wqt = (short*)(ws + 4 * SZ);            // [4SZ,4.5SZ): 3xCD*CD + CD*CD
    short* wot = wqt + 3 * CD * CD;
    short* w1t = (short*)(ws + 4 * SZ + SZ / 2);   // [4.5SZ,5SZ)
    short* w2t = (short*)(ws + 5 * SZ);            // [5SZ,5.5SZ)
    short* vtg = (short*)(ws + 5 * SZ + SZ / 2);   // [5.5SZ,6SZ): V^T global
    short* ff1 = (short*)ws;                       // [0,2SZ): reuses dead q/k/v

    // 1) h1 = LN(x)  (bf16)
    ln_kernel<<<BT, 256, 0, stream>>>(x, g1, be1, h);

    // 2) all weight transposes fused (bf16 B^T layouts)
    prep_weights<<<3072, 256, 0, stream>>>(Wq, Wk, Wv, Wo, W1, W2, wqt, wot, w1t, w2t);

    // 3) merged q|k|v = h1 @ [Wq|Wk|Wv]  (bf16; C^-0.5*log2e folded into q)
    gemm_mfma<5, 128, 1><<<dim3(24, 32), 256, 0, stream>>>(h, wqt, nullptr, nullptr, nullptr, qbf, 3 * CD, CD);

    // 4) vtg = V^T per (b,h)
    vtrans<<<dim3(TD / 64, 2 * NH), 256, 0, stream>>>(vbf, vtg);

    // 5) attention split-K -> opart, lpart
    attn_mfma<<<dim3(TD / BQ, NH, BB * 2), 256, 0, stream>>>(qbf, kbf, vtg, opart, lpart);

    // 6) combine -> ob (bf16, concat-head layout)
    attn_combine<<<dim3((int)(SZ / (256 * 8))), 256, 0, stream>>>(opart, lpart, ob);

    // 7) x1 = ob @ Wo + bo + x  (fp32; 512-thr in-block split-K, depth-3)
    gemm_mfma<1, 128, 2><<<dim3(8, 32), 512, 0, stream>>>(ob, wot, bo, x, x1, nullptr, CD, CD);

    // 8) h2 = LN(x1)  (bf16)
    ln_kernel<<<BT, 256, 0, stream>>>(x1, g2, be2, h);

    // 9) ff1 = relu(h2 @ W1 + b1)  (bf16, N=4096; 128x256 tile, 2 blocks/CU)
    gemm_mfma<2, 256, 1><<<dim3(16, 32), 256, 0, stream>>>(h, w1t, b1, nullptr, nullptr, ff1, 4 * CD, CD);

    // 10) out = ff1 @ W2 + b2 + x1  (fp32, K=4096; 1024-thr 4-way in-block
    //     split-K: 16 waves/CU at the grid-forced 1 block/CU)
    gemm_mfma<1, 128, 4><<<dim3(8, 32), 1024, 0, stream>>>(ff1, w2t, b2, x1, out, nullptr, CD, 4 * CD);
}

// Round 13
// 313.495 us; speedup vs baseline: 1.0464x; 1.0464x over previous
//
#include <hip/hip_runtime.h>
#include <hip/hip_bf16.h>

#define BT   4096   // B*T
#define CD   1024   // C
#define TD   2048   // T
#define NH   16     // heads
#define DH   64     // head dim
#define BB   2      // batch

typedef __attribute__((ext_vector_type(8))) short bf16x8;
typedef __attribute__((ext_vector_type(4))) short bf16x4;
typedef __attribute__((ext_vector_type(4))) float f32x4;
typedef __attribute__((ext_vector_type(2))) unsigned int u32x2;
typedef __attribute__((ext_vector_type(4))) unsigned int u32x4;

__device__ inline short f2bf(float f) {
    union { float fv; unsigned u; } x; x.fv = f;
    unsigned r = x.u + 0x7fffu + ((x.u >> 16) & 1u);
    return (short)(r >> 16);
}
__device__ inline float bf2f(short s) {
    union { unsigned u; float f; } x; x.u = ((unsigned)(unsigned short)s) << 16;
    return x.f;
}
__device__ inline unsigned pk2bf(float a, float b) {
    union { __hip_bfloat162 h; unsigned u; } cv;
    cv.h = __float22bfloat162_rn(float2{a, b});
    return cv.u;
}

// raw v_exp_f32 (2^x): avoid any OCML guard sequence
#if __has_builtin(__builtin_amdgcn_exp2f)
#define EXP2(x) __builtin_amdgcn_exp2f(x)
#else
#define EXP2(x) exp2f(x)
#endif

__device__ inline void gload_lds16(const short* g, short* lds) {
    __builtin_amdgcn_global_load_lds(
        (const __attribute__((address_space(1))) void*)g,
        (__attribute__((address_space(3))) void*)lds, 16, 0, 0);
}

// ---------------- LayerNorm: one block per row (C=1024), fp32 in, bf16 out ----
// float4 loads (one per thread), row kept in regs, short4 output store.
__launch_bounds__(256)
__global__ void ln_kernel(const float* __restrict__ x,
                          const float* __restrict__ g,
                          const float* __restrict__ be,
                          short* __restrict__ out) {
    __shared__ float red[2][4];
    const int row = blockIdx.x;
    const int c4 = threadIdx.x * 4;
    const float* xr = x + (size_t)row * CD;
    float4 v = *(const float4*)&xr[c4];
    float s  = (v.x + v.y) + (v.z + v.w);
    float ss = (v.x * v.x + v.y * v.y) + (v.z * v.z + v.w * v.w);
    #pragma unroll
    for (int off = 32; off > 0; off >>= 1) {
        s  += __shfl_down(s,  off, 64);
        ss += __shfl_down(ss, off, 64);
    }
    int wid = threadIdx.x >> 6, lane = threadIdx.x & 63;
    if (lane == 0) { red[0][wid] = s; red[1][wid] = ss; }
    __syncthreads();
    float sum   = red[0][0] + red[0][1] + red[0][2] + red[0][3];
    float sumsq = red[1][0] + red[1][1] + red[1][2] + red[1][3];
    float mu   = sum * (1.f / CD);
    float var  = sumsq * (1.f / CD) - mu * mu;
    float rstd = rsqrtf(var + 1e-5f);
    float4 gv = *(const float4*)&g[c4];
    float4 bv = *(const float4*)&be[c4];
    bf16x4 o;
    o[0] = f2bf((v.x - mu) * rstd * gv.x + bv.x);
    o[1] = f2bf((v.y - mu) * rstd * gv.y + bv.y);
    o[2] = f2bf((v.z - mu) * rstd * gv.z + bv.z);
    o[3] = f2bf((v.w - mu) * rstd * gv.w + bv.w);
    *(bf16x4*)&out[(size_t)row * CD + c4] = o;
}

// ------------- Fused weight prep: all 64x64 fp32->bf16 transpose tiles -------
// blocks 0..767: Wq/Wk/Wv (per-head CDxDH slices) -> wqt (3,H,DH,C)
// 768..1023: Wo (CDxCD); 1024..2047: W1 (CDx4CD); 2048..3071: W2 (4CDxCD)
__launch_bounds__(256)
__global__ void prep_weights(const float* __restrict__ Wq, const float* __restrict__ Wk,
                             const float* __restrict__ Wv, const float* __restrict__ Wo,
                             const float* __restrict__ W1, const float* __restrict__ W2,
                             short* __restrict__ wqt, short* __restrict__ wot,
                             short* __restrict__ w1t, short* __restrict__ w2t) {
    __shared__ float tt[64][65];
    const int id = blockIdx.x;
    const float* in; short* out; int R, Cc, r0, c0;
    if (id < 768) {
        int which = id >> 8, rem = id & 255, hh = rem >> 4, ry = rem & 15;
        in  = (which == 0 ? Wq : which == 1 ? Wk : Wv) + (size_t)hh * CD * DH;
        out = wqt + (size_t)which * CD * CD + (size_t)hh * DH * CD;
        R = CD; Cc = DH; r0 = ry * 64; c0 = 0;
    } else if (id < 1024) {
        int t = id - 768;  in = Wo; out = wot; R = CD;     Cc = CD;     r0 = (t >> 4) * 64; c0 = (t & 15) * 64;
    } else if (id < 2048) {
        int t = id - 1024; in = W1; out = w1t; R = CD;     Cc = 4 * CD; r0 = (t >> 6) * 64; c0 = (t & 63) * 64;
    } else {
        int t = id - 2048; in = W2; out = w2t; R = 4 * CD; Cc = CD;     r0 = (t >> 4) * 64; c0 = (t & 15) * 64;
    }
    const int tid = threadIdx.x;
    #pragma unroll
    for (int i = 0; i < 4; ++i) {
        int f = i * 256 + tid;             // float4 index within 64x64 tile
        int r = f >> 4, cc = (f & 15) * 4;
        float4 vv = *(const float4*)&in[(size_t)(r0 + r) * Cc + c0 + cc];
        tt[r][cc]     = vv.x;
        tt[r][cc + 1] = vv.y;
        tt[r][cc + 2] = vv.z;
        tt[r][cc + 3] = vv.w;
    }
    __syncthreads();
    #pragma unroll
    for (int i = 0; i < 16; ++i) {
        int e = i * 256 + tid;
        out[(size_t)(c0 + (e >> 6)) * R + r0 + (e & 63)] = f2bf(tt[e & 63][e >> 6]);
    }
}

// ------------- V transpose: vbf (BT x C bf16) -> vtg[b][h][d][t] bf16 -------
__launch_bounds__(256)
__global__ void vtrans(const short* __restrict__ vin, short* __restrict__ vout) {
    __shared__ short t[64 * 65];
    const int tid = threadIdx.x;
    const int bh = blockIdx.y;
    const int t0 = blockIdx.x * 64;
    const int b = bh >> 4, h = bh & 15;
    const short* src = vin + (size_t)b * TD * CD + (size_t)h * DH;
    short* dst = vout + (size_t)bh * DH * TD;
    #pragma unroll
    for (int i = 0; i < 16; ++i) {
        int e = i * 256 + tid;
        t[(e >> 6) * 65 + (e & 63)] = src[(size_t)(t0 + (e >> 6)) * CD + (e & 63)];
    }
    __syncthreads();
    #pragma unroll
    for (int i = 0; i < 16; ++i) {
        int e = i * 256 + tid;
        int d = e >> 6, tt = e & 63;
        dst[(size_t)d * TD + t0 + tt] = t[tt * 65 + d];
    }
}

// ---------------- MFMA GEMM: C(128 x TN) = A(M x K) . Bt(N x K)^T, bf16 ------
// GR=1: triple-buffered, depth-2 prefetch (vmcnt 4/6).
// GR=2 (512 thr): in-block split-K, 4 buffers/group, depth-3, vmcnt(8)
//   (measured best for the 256-block MODE-1 GEMMs; GR=4 regressed: NBUF=2
//   cut prefetch depth and added barriers -- depth beats waves past 8/CU).
// XOR-swizzled 16B slots -> conflict-free ds_read_b128, linear gload dest.
// XCD-aware tile swizzle: XCD k = li&7 owns m-tiles [4k,4k+4) x all n-tiles.
// MODE 1: + bias + fp32 resid -> fp32 out
// MODE 2: + bias, relu -> bf16 out
// MODE 5: QKV merged: N=3072; seg=col>>10 -> outb + seg*BT*CD; seg0 scaled
template <int MODE, int TN, int GR>
__launch_bounds__(GR * 256)
__global__ void gemm_mfma(const short* __restrict__ A,
                          const short* __restrict__ Bt,
                          const float* __restrict__ bias,
                          const float* __restrict__ resid,
                          float* __restrict__ outf,
                          short* __restrict__ outb,
                          int N, int K) {
    constexpr int NBUF = (GR == 2) ? 4 : 3;
    __shared__ __align__(16) short smem[GR * NBUF * (128 + TN) * 32];
    const int tid = threadIdx.x;
    const int kgrp = (GR == 2) ? (tid >> 8) : 0;
    const int tid256 = tid & 255;
    const int w4 = tid256 >> 6, lane = tid & 63;
    const int quad = lane >> 4, l16 = lane & 15;
    const int wr = w4 >> 1, wc = w4 & 1;
    // XCD-aware swizzle: li -> (m-tile, n-tile); XCD k = li&7 owns m 4k..4k+4
    const int li = blockIdx.y * gridDim.x + blockIdx.x;
    const int m0 = ((li & 7) * 4 + ((li >> 3) & 3)) * 128;
    const int n0 = (li >> 5) * TN;
    const int NT = TN / 32;
    const int kbase = kgrp * (K / GR);

    short* grpBase = smem + (size_t)kgrp * NBUF * (128 + TN) * 32;
#define AS(bi) (grpBase + (bi) * (128 + TN) * 32)
#define BS(bi) (AS(bi) + 128 * 32)

    f32x4 acc[4][NT] = {};

    auto STAGE = [&](int kt, int bi) {
        const int k0 = kbase + kt * 32;
        short* as = AS(bi);
        short* bs = BS(bi);
        #pragma unroll
        for (int i = 0; i < 2; ++i) {
            int s = i * 256 + tid256;
            int row = s >> 2, kc = (s & 3) ^ ((row >> 1) & 3);
            gload_lds16(A + (size_t)(m0 + row) * K + k0 + kc * 8,
                        &as[(i * 256 + w4 * 64) * 8]);
        }
        #pragma unroll
        for (int i = 0; i < TN / 64; ++i) {
            int s = i * 256 + tid256;
            int row = s >> 2, kc = (s & 3) ^ ((row >> 1) & 3);
            gload_lds16(Bt + (size_t)(n0 + row) * K + k0 + kc * 8,
                        &bs[(i * 256 + w4 * 64) * 8]);
        }
    };

    auto COMPUTE = [&](int bi) {
        const int xo = (quad ^ ((l16 >> 1) & 3)) * 8;
        const short* as = AS(bi);
        const short* bs = BS(bi);
        bf16x8 a[4], b[NT];
        #pragma unroll
        for (int mt = 0; mt < 4; ++mt)
            a[mt] = *(const bf16x8*)&as[(wr * 64 + mt * 16 + l16) * 32 + xo];
        #pragma unroll
        for (int nt = 0; nt < NT; ++nt)
            b[nt] = *(const bf16x8*)&bs[(wc * (TN / 2) + nt * 16 + l16) * 32 + xo];
        #pragma unroll
        for (int mt = 0; mt < 4; ++mt)
            #pragma unroll
            for (int nt = 0; nt < NT; ++nt)
                acc[mt][nt] = __builtin_amdgcn_mfma_f32_16x16x32_bf16(a[mt], b[nt], acc[mt][nt], 0, 0, 0);
    };

    const int nk = (K / GR) >> 5;
    if (GR == 2) {
        // depth-3: tiles t, t+1, t+2 in flight (4 loads each per thread)
        STAGE(0, 0);
        STAGE(1, 1);
        STAGE(2, 2);
        for (int t = 0; t < nk - 2; ++t) {
            asm volatile("s_waitcnt vmcnt(8)" ::: "memory");
            __builtin_amdgcn_s_barrier();
            asm volatile("" ::: "memory");
            if (t + 3 < nk) STAGE(t + 3, (t + 3) & 3);
            COMPUTE(t & 3);
        }
        asm volatile("s_waitcnt vmcnt(4)" ::: "memory");
        __builtin_amdgcn_s_barrier();
        asm volatile("" ::: "memory");
        COMPUTE((nk - 2) & 3);
        asm volatile("s_waitcnt vmcnt(0)" ::: "memory");
        __builtin_amdgcn_s_barrier();
        asm volatile("" ::: "memory");
        COMPUTE((nk - 1) & 3);
    } else {
        // depth-2, 3 buffers
        STAGE(0, 0);
        STAGE(1, 1);
        int bi = 0;
        for (int t = 0; t < nk - 1; ++t) {
            if (TN == 256) asm volatile("s_waitcnt vmcnt(6)" ::: "memory");
            else           asm volatile("s_waitcnt vmcnt(4)" ::: "memory");
            __builtin_amdgcn_s_barrier();
            asm volatile("" ::: "memory");
            int bn = bi + 2 >= 3 ? bi - 1 : bi + 2;
            if (t + 2 < nk) STAGE(t + 2, bn);
            COMPUTE(bi);
            bi = bi + 1 >= 3 ? 0 : bi + 1;
        }
        asm volatile("s_waitcnt vmcnt(0)" ::: "memory");
        __builtin_amdgcn_s_barrier();
        asm volatile("" ::: "memory");
        COMPUTE(bi);
    }

    if (GR == 2) {
        // cross-group reduction: group1 acc -> LDS (slice-major, conflict-free)
        float* red = (float*)smem;
        __syncthreads();   // staging LDS dead; safe to alias
        if (kgrp == 1) {
            #pragma unroll
            for (int mt = 0; mt < 4; ++mt)
                #pragma unroll
                for (int nt = 0; nt < NT; ++nt)
                    *(f32x4*)&red[((mt * NT + nt) * 256 + w4 * 64 + lane) * 4] = acc[mt][nt];
        }
        __syncthreads();
        if (kgrp == 1) return;
        #pragma unroll
        for (int mt = 0; mt < 4; ++mt)
            #pragma unroll
            for (int nt = 0; nt < NT; ++nt) {
                f32x4 p = *(const f32x4*)&red[((mt * NT + nt) * 256 + w4 * 64 + lane) * 4];
                acc[mt][nt] += p;
            }
    }

    const float qsc = (MODE == 5 && n0 < CD) ? 0.03125f * 1.44269504f : 1.0f;
    short* ob5 = (MODE == 5) ? outb + (size_t)(n0 >> 10) * BT * CD : nullptr;

    #pragma unroll
    for (int mt = 0; mt < 4; ++mt)
        #pragma unroll
        for (int nt = 0; nt < NT; ++nt)
            #pragma unroll
            for (int reg = 0; reg < 4; ++reg) {
                int row = m0 + wr * 64 + mt * 16 + quad * 4 + reg;
                int col = n0 + wc * (TN / 2) + nt * 16 + l16;
                float v = acc[mt][nt][reg];
                if (MODE == 1) { v += bias[col] + resid[(size_t)row * N + col];
                                 outf[(size_t)row * N + col] = v; }
                if (MODE == 2) { v = fmaxf(v + bias[col], 0.f);
                                 outb[(size_t)row * N + col] = f2bf(v); }
                if (MODE == 5) { ob5[(size_t)row * CD + (col & 1023)] = f2bf(v * qsc); }
            }
#undef AS
#undef BS
}

// -------- 256x256-tile GEMM (8 waves, 512 thr): ff1 = relu(h @ W1 + b1) -----
// R21: FF1-dedicated. M=N=4096 -> grid 256 = exactly 1 block/CU, 8 waves in
// a 2x4 grid (per-wave 128x64 out, acc[8][4]). Same proven skeleton: triple
// buffer, depth-2 counted vmcnt(4), XOR-swizzled 16B slots, linear gload
// dest. vs the 128x256 version: staging 6->4 loads/thread/step at the same
// 32 MFMA/wave/step, A-panel reuse doubled. Bijective XCD swizzle for the
// 16x16 tile grid: mt=(li&7)*2+((li>>3)&1), nt=li>>4.
__launch_bounds__(512, 1)
__global__ void gemm_256(const short* __restrict__ A,
                         const short* __restrict__ Bt,
                         const float* __restrict__ bias,
                         short* __restrict__ outb,
                         int N, int K) {
    __shared__ __align__(16) short smem[3 * 512 * 32];   // 96 KB
    const int tid = threadIdx.x;
    const int w = tid >> 6, lane = tid & 63;
    const int quad = lane >> 4, l16 = lane & 15;
    const int wr = w >> 2, wc = w & 3;
    const int li = blockIdx.x;
    const int m0 = ((li & 7) * 2 + ((li >> 3) & 1)) * 256;
    const int n0 = (li >> 4) * 256;

#define AS6(bi) (smem + (bi) * 512 * 32)
#define BS6(bi) (AS6(bi) + 256 * 32)

    f32x4 acc[8][4] = {};

    auto STAGE = [&](int kt, int bi) {
        const int k0 = kt * 32;
        short* as = AS6(bi);
        short* bs = BS6(bi);
        #pragma unroll
        for (int i = 0; i < 2; ++i) {
            int s = i * 512 + tid;
            int row = s >> 2, kc = (s & 3) ^ ((row >> 1) & 3);
            gload_lds16(A + (size_t)(m0 + row) * K + k0 + kc * 8,
                        &as[(i * 512 + w * 64) * 8]);
        }
        #pragma unroll
        for (int i = 0; i < 2; ++i) {
            int s = i * 512 + tid;
            int row = s >> 2, kc = (s & 3) ^ ((row >> 1) & 3);
            gload_lds16(Bt + (size_t)(n0 + row) * K + k0 + kc * 8,
                        &bs[(i * 512 + w * 64) * 8]);
        }
    };

    auto COMPUTE = [&](int bi) {
        const int xo = (quad ^ ((l16 >> 1) & 3)) * 8;
        const short* as = AS6(bi);
        const short* bs = BS6(bi);
        bf16x8 a[8], b[4];
        #pragma unroll
        for (int mt = 0; mt < 8; ++mt)
            a[mt] = *(const bf16x8*)&as[(wr * 128 + mt * 16 + l16) * 32 + xo];
        #pragma unroll
        for (int nt = 0; nt < 4; ++nt)
            b[nt] = *(const bf16x8*)&bs[(wc * 64 + nt * 16 + l16) * 32 + xo];
        #pragma unroll
        for (int mt = 0; mt < 8; ++mt)
            #pragma unroll
            for (int nt = 0; nt < 4; ++nt)
                acc[mt][nt] = __builtin_amdgcn_mfma_f32_16x16x32_bf16(a[mt], b[nt], acc[mt][nt], 0, 0, 0);
    };

    const int nk = K >> 5;
    STAGE(0, 0);
    STAGE(1, 1);
    int bi = 0;
    for (int t = 0; t < nk - 1; ++t) {
        // tile t landed; tile t+1's 4 loads (youngest) still flying
        asm volatile("s_waitcnt vmcnt(4)" ::: "memory");
        __builtin_amdgcn_s_barrier();
        asm volatile("" ::: "memory");
        int bn = bi + 2 >= 3 ? bi - 1 : bi + 2;
        if (t + 2 < nk) STAGE(t + 2, bn);
        COMPUTE(bi);
        bi = bi + 1 >= 3 ? 0 : bi + 1;
    }
    asm volatile("s_waitcnt vmcnt(0)" ::: "memory");
    __builtin_amdgcn_s_barrier();
    asm volatile("" ::: "memory");
    COMPUTE(bi);

    #pragma unroll
    for (int mt = 0; mt < 8; ++mt)
        #pragma unroll
        for (int nt = 0; nt < 4; ++nt)
            #pragma unroll
            for (int reg = 0; reg < 4; ++reg) {
                int row = m0 + wr * 128 + mt * 16 + quad * 4 + reg;
                int col = n0 + wc * 64 + nt * 16 + l16;
                float v = fmaxf(acc[mt][nt][reg] + bias[col], 0.f);
                outb[(size_t)row * N + col] = f2bf(v);
            }
#undef AS6
#undef BS6
}

// ---------------- Flash attention, split-K, MFMA bf16, no-max softmax --------
// R9 version (best measured attn: 49.2us, FETCH 69.7MB): staging via
// global_load_lds (T21 source permutation; LDS dest linear), BK=32 unpadded
// 8KB buffers, TRIPLE-buffered, counted vmcnt(2) never-drain, 5 blocks/CU.
// Swizzles (2-way max = free):
//   K [32][64]: store chunk c' = c ^ (row&7);  read chunk x ^ (l16&7)
//   V [64][32]: store chunk c' = c ^ ((row>>1)&3); read chunk quad^((l16>>1)&3)
// K=32 PV via permuted-K storage (R14) and l-sum via MFMA ones (R15).
#define BQ   128
#define BK   32

__launch_bounds__(256, 5)
__global__ void attn_mfma(const short* __restrict__ q,
                          const short* __restrict__ k,
                          const short* __restrict__ vt,
                          short* __restrict__ opart,
                          float* __restrict__ lpart) {
    __shared__ short Ks[3][BK * DH];   // [32][64]
    __shared__ short Vt[3][DH * BK];   // [64][32]

    const int tid  = threadIdx.x;
    const int w = tid >> 6, lane = tid & 63;
    const int quad = lane >> 4, l16 = lane & 15;
    const int h = blockIdx.y;
    const int b = blockIdx.z >> 1, split = blockIdx.z & 1;
    const int q0 = blockIdx.x * BQ;
    const size_t base  = (size_t)b * TD * CD + (size_t)h * DH;
    const size_t vbase = (size_t)(b * NH + h) * DH * TD;

    // Q frags (N-side of S^T mfma): lane holds Q[q=l16][d=quad*8+j]
    bf16x8 qf[2][2];
    #pragma unroll
    for (int rt = 0; rt < 2; ++rt) {
        const short* qp = q + base + (size_t)(q0 + w * 32 + rt * 16 + l16) * CD;
        qf[rt][0] = *(const bf16x8*)&qp[quad * 8];
        qf[rt][1] = *(const bf16x8*)&qp[32 + quad * 8];
    }

    const bf16x8 ones = {(short)0x3F80, (short)0x3F80, (short)0x3F80, (short)0x3F80,
                         (short)0x3F80, (short)0x3F80, (short)0x3F80, (short)0x3F80};
    f32x4 O_l[2] = {};   // l accumulator: row q=quad*4+reg (col replicated)
    f32x4 O[2][4] = {};

    const int kbeg = split * (TD / 2);
    const int NTI = (TD / 2) / BK;   // 32

    // --- per-lane staging source coords (computed once) ---
    const int ks  = tid >> 3;
    const int kc  = (tid & 7) ^ (ks & 7);
    const int kkey = (((ks & 15) >> 2) << 3) + (ks & 3) + ((ks >> 4) << 2);
    const short* kgp = k + base + (size_t)kkey * CD + kc * 8;   // + (kbeg+kt*BK)*CD
    const int vd = tid >> 2;
    const int vc = (tid & 3) ^ ((vd >> 1) & 3);
    const short* vgp = vt + vbase + (size_t)vd * TD + vc * 8;   // + kbeg+kt*BK

#define STAGE_T(kt, bi) do {                                              \
        const size_t ko_ = (size_t)(kbeg + (kt) * BK);                    \
        gload_lds16(kgp + ko_ * CD, &Ks[bi][w * 512]);                    \
        gload_lds16(vgp + ko_,      &Vt[bi][w * 512]);                    \
    } while (0)

#define COMPUTE_T(bi) do {                                                \
        __builtin_amdgcn_s_setprio(1);                                    \
        const int kswz = l16 & 7;                                         \
        bf16x8 kbe0 = *(const bf16x8*)&Ks[bi][l16 * 64 + ((quad) ^ kswz) * 8];        \
        bf16x8 kbe1 = *(const bf16x8*)&Ks[bi][l16 * 64 + ((4 + quad) ^ kswz) * 8];    \
        bf16x8 kbo0 = *(const bf16x8*)&Ks[bi][(16 + l16) * 64 + ((quad) ^ kswz) * 8]; \
        bf16x8 kbo1 = *(const bf16x8*)&Ks[bi][(16 + l16) * 64 + ((4 + quad) ^ kswz) * 8]; \
        bf16x8 pa8[2];                                                    \
        _Pragma("unroll")                                                 \
        for (int rt = 0; rt < 2; ++rt) {                                  \
            f32x4 ae = (f32x4){0.f, 0.f, 0.f, 0.f};                       \
            f32x4 ao = (f32x4){0.f, 0.f, 0.f, 0.f};                       \
            ae = __builtin_amdgcn_mfma_f32_16x16x32_bf16(kbe0, qf[rt][0], ae, 0, 0, 0); \
            ae = __builtin_amdgcn_mfma_f32_16x16x32_bf16(kbe1, qf[rt][1], ae, 0, 0, 0); \
            ao = __builtin_amdgcn_mfma_f32_16x16x32_bf16(kbo0, qf[rt][0], ao, 0, 0, 0); \
            ao = __builtin_amdgcn_mfma_f32_16x16x32_bf16(kbo1, qf[rt][1], ao, 0, 0, 0); \
            float pe0 = EXP2(ae[0]), pe1 = EXP2(ae[1]);                   \
            float pe2 = EXP2(ae[2]), pe3 = EXP2(ae[3]);                   \
            float po0 = EXP2(ao[0]), po1 = EXP2(ao[1]);                   \
            float po2 = EXP2(ao[2]), po3 = EXP2(ao[3]);                   \
            union { u32x4 u; bf16x8 s; } cv_;                             \
            cv_.u = (u32x4){pk2bf(pe0, pe1), pk2bf(pe2, pe3),             \
                            pk2bf(po0, po1), pk2bf(po2, po3)};            \
            pa8[rt] = cv_.s;                                              \
        }                                                                 \
        const int vswz = (l16 >> 1) & 3;                                  \
        _Pragma("unroll")                                                 \
        for (int dt = 0; dt < 4; ++dt) {                                  \
            bf16x8 vb = *(const bf16x8*)&Vt[bi][(dt * 16 + l16) * 32 + ((quad) ^ vswz) * 8]; \
            O[0][dt] = __builtin_amdgcn_mfma_f32_16x16x32_bf16(pa8[0], vb, O[0][dt], 0, 0, 0); \
            O[1][dt] = __builtin_amdgcn_mfma_f32_16x16x32_bf16(pa8[1], vb, O[1][dt], 0, 0, 0); \
        }                                                                 \
        O_l[0] = __builtin_amdgcn_mfma_f32_16x16x32_bf16(pa8[0], ones, O_l[0], 0, 0, 0); \
        O_l[1] = __builtin_amdgcn_mfma_f32_16x16x32_bf16(pa8[1], ones, O_l[1], 0, 0, 0); \
        __builtin_amdgcn_s_setprio(0);                                    \
    } while (0)

    // prologue: tiles 0,1 in flight (2 gload_lds each per thread)
    STAGE_T(0, 0);
    STAGE_T(1, 1);
    int bi = 0;
    for (int t = 0; t < NTI - 1; ++t) {
        // counted wait: tile t's 2 loads done; tile t+1's 2 (youngest) fly
        asm volatile("s_waitcnt vmcnt(2)" ::: "memory");
        __builtin_amdgcn_s_barrier();
        asm volatile("" ::: "memory");
        int bn = bi + 2 >= 3 ? bi - 1 : bi + 2;
        if (t + 2 < NTI) STAGE_T(t + 2, bn);
        COMPUTE_T(bi);
        bi = bi + 1 >= 3 ? 0 : bi + 1;
    }
    asm volatile("s_waitcnt vmcnt(0)" ::: "memory");
    __builtin_amdgcn_s_barrier();
    asm volatile("" ::: "memory");
    COMPUTE_T(bi);
#undef STAGE_T
#undef COMPUTE_T

    // epilogue: unnormalized O (bf16) + l (fp32) per split
    short* osp = opart + (size_t)split * BT * CD;
    float* lsp = lpart + (size_t)split * BB * NH * TD + (size_t)(b * NH + h) * TD;
    #pragma unroll
    for (int rt = 0; rt < 2; ++rt) {
        if (l16 == 0)
            *(f32x4*)&lsp[q0 + w * 32 + rt * 16 + quad * 4] = O_l[rt];
        #pragma unroll
        for (int reg = 0; reg < 4; ++reg) {
            int row = q0 + w * 32 + rt * 16 + quad * 4 + reg;
            short* op = osp + base + (size_t)row * CD;
            #pragma unroll
            for (int dt = 0; dt < 4; ++dt)
                op[dt * 16 + l16] = f2bf(O[rt][dt][reg]);
        }
    }
}

// ---------------- Combine split-K partials: ob = (O0+O1)/(l0+l1), bf16 -------
__launch_bounds__(256)
__global__ void attn_combine(const short* __restrict__ opart,
                             const float* __restrict__ lpart,
                             short* __restrict__ ob) {
    const size_t idx = ((size_t)blockIdx.x * 256 + threadIdx.x) * 8;
    const int row = (int)(idx >> 10);        // / CD
    const int col = (int)(idx & 1023);
    const int b = row >> 11, qq = row & (TD - 1), hh = col >> 6;
    const size_t lbase = (size_t)(b * NH + hh) * TD + qq;
    const float l0 = lpart[lbase];
    const float l1 = lpart[(size_t)BB * NH * TD + lbase];
    const float inv = 1.f / (l0 + l1);
    bf16x8 a = *(const bf16x8*)&opart[idx];
    bf16x8 c = *(const bf16x8*)&opart[(size_t)BT * CD + idx];
    bf16x8 r;
    #pragma unroll
    for (int j = 0; j < 8; ++j)
        r[j] = f2bf((bf2f(a[j]) + bf2f(c[j])) * inv);
    *(bf16x8*)&ob[idx] = r;
}

extern "C" void kernel_launch(void* const* d_in, const int* in_sizes, int n_in,
                              void* d_out, int out_size, void* d_ws, size_t ws_size,
                              hipStream_t stream) {
    const float* x   = (const float*)d_in[0];
    const float* Wq  = (const float*)d_in[1];
    const float* Wk  = (const float*)d_in[2];
    const float* Wv  = (const float*)d_in[3];
    const float* Wo  = (const float*)d_in[4];
    const float* bo  = (const float*)d_in[5];
    const float* W1  = (const float*)d_in[6];
    const float* b1  = (const float*)d_in[7];
    const float* W2  = (const float*)d_in[8];
    const float* b2  = (const float*)d_in[9];
    const float* g1  = (const float*)d_in[10];
    const float* be1 = (const float*)d_in[11];
    const float* g2  = (const float*)d_in[12];
    const float* be2 = (const float*)d_in[13];
    float* out = (float*)d_out;

    const size_t SZ = (size_t)BT * CD;  // 4M elements
    float* ws  = (float*)d_ws;
    short* qbf = (short*)ws;                       // [0,1.5SZ): q|k|v bf16
    short* kbf = qbf + SZ;
    short* vbf = qbf + 2 * SZ;
    float* lpart = ws + SZ + SZ / 2;               // [1.5SZ,+128K floats)
    short* opart = (short*)(ws + 2 * SZ);          // [2SZ,3SZ): 2 x SZ bf16
    float* x1  = ws + 2 * SZ;                      // [2SZ,3SZ): after combine
    short* h   = (short*)(ws + 3 * SZ);            // [3SZ,3.5SZ)
    short* ob  = (short*)(ws + 3 * SZ + SZ / 2);   // [3.5SZ,4SZ)
    short* wqt = (short*)(ws + 4 * SZ);            // [4SZ,4.5SZ): 3xCD*CD + CD*CD
    short* wot = wqt + 3 * CD * CD;
    short* w1t = (short*)(ws + 4 * SZ + SZ / 2);   // [4.5SZ,5SZ)
    short* w2t = (short*)(ws + 5 * SZ);            // [5SZ,5.5SZ)
    short* vtg = (short*)(ws + 5 * SZ + SZ / 2);   // [5.5SZ,6SZ): V^T global
    short* ff1 = (short*)ws;                       // [0,2SZ): reuses dead q/k/v

    // 1) h1 = LN(x)  (bf16)
    ln_kernel<<<BT, 256, 0, stream>>>(x, g1, be1, h);

    // 2) all weight transposes fused (bf16 B^T layouts)
    prep_weights<<<3072, 256, 0, stream>>>(Wq, Wk, Wv, Wo, W1, W2, wqt, wot, w1t, w2t);

    // 3) merged q|k|v = h1 @ [Wq|Wk|Wv]  (bf16; C^-0.5*log2e folded into q)
    gemm_mfma<5, 128, 1><<<dim3(24, 32), 256, 0, stream>>>(h, wqt, nullptr, nullptr, nullptr, qbf, 3 * CD, CD);

    // 4) vtg = V^T per (b,h)
    vtrans<<<dim3(TD / 64, 2 * NH), 256, 0, stream>>>(vbf, vtg);

    // 5) attention split-K -> opart, lpart
    attn_mfma<<<dim3(TD / BQ, NH, BB * 2), 256, 0, stream>>>(qbf, kbf, vtg, opart, lpart);

    // 6) combine -> ob (bf16, concat-head layout)
    attn_combine<<<dim3((int)(SZ / (256 * 8))), 256, 0, stream>>>(opart, lpart, ob);

    // 7) x1 = ob @ Wo + bo + x  (fp32; 512-thr in-block split-K, depth-3)
    gemm_mfma<1, 128, 2><<<dim3(8, 32), 512, 0, stream>>>(ob, wot, bo, x, x1, nullptr, CD, CD);

    // 8) h2 = LN(x1)  (bf16)
    ln_kernel<<<BT, 256, 0, stream>>>(x1, g2, be2, h);

    // 9) ff1 = relu(h2 @ W1 + b1)  (bf16, N=4096; 256x256 tile, 8 waves,
    //    1 block/CU even grid)
    gemm_256<<<256, 512, 0, stream>>>(h, w1t, b1, ff1, 4 * CD, CD);

    // 10) out = ff1 @ W2 + b2 + x1  (fp32, K=4096, in-block split-K, depth-3)
    gemm_mfma<1, 128, 2><<<dim3(8, 32), 512, 0, stream>>>(ff1, w2t, b2, x1, out, nullptr, CD, 4 * CD);
}